// Round 3
// baseline (1325.218 us; speedup 1.0000x reference)
//
#include <hip/hip_runtime.h>
#include <stdint.h>

// B=128 samples, C=512 channels, HW=1024 tokens.
// LN over full (C,HW) per sample; token-MLP: relu(t@w1^T+b1)@w2^T+b2.
// Input/output dtype detected at runtime (bf16 vs f32) via device-side flag.

#define NSAMP 128
#define CCH   512
#define HWSZ  1024
#define NPER  (CCH*HWSZ)   // 524288 elements per sample

typedef unsigned short u16;
typedef __bf16 bf16x8 __attribute__((ext_vector_type(8)));
typedef float  f32x4  __attribute__((ext_vector_type(4)));

__device__ __forceinline__ float b2f(u16 h){ return __uint_as_float(((unsigned)h)<<16); }
__device__ __forceinline__ u16 f2b(float f){
  unsigned u = __float_as_uint(f);
  u += 0x7FFFu + ((u>>16)&1u);   // RNE
  return (u16)(u>>16);
}
__device__ __forceinline__ void unpack8(uint4 v, float* f){
  const unsigned* u = (const unsigned*)&v;
#pragma unroll
  for (int q=0;q<4;q++){
    f[2*q]   = __uint_as_float(u[q]<<16);
    f[2*q+1] = __uint_as_float(u[q]&0xFFFF0000u);
  }
}
// dual-dtype 8-element loader; idx in ELEMENTS of the source dtype
__device__ __forceinline__ void load8(const void* base, size_t idx, int isf, float* f){
  if (isf){
    const float* p = (const float*)base + idx;
    uint4 a = *(const uint4*)p;
    uint4 b = *(const uint4*)(p+4);
    const float* af = (const float*)&a;
    const float* bf = (const float*)&b;
#pragma unroll
    for (int j=0;j<4;j++){ f[j]=af[j]; f[4+j]=bf[j]; }
  } else {
    uint4 v = *(const uint4*)((const u16*)base + idx);
    unpack8(v, f);
  }
}
__device__ __forceinline__ void store8b(u16* dst, const float* f){
  uint4 o; unsigned* ou = (unsigned*)&o;
#pragma unroll
  for (int q=0;q<4;q++) ou[q] = (unsigned)f2b(f[2*q]) | ((unsigned)f2b(f[2*q+1])<<16);
  *(uint4*)dst = o;
}

// ---------------- K0: dtype detect ----------------
// bf16 N(0,1): exponent field never >= 0xC0. f32 read as u16 stream: low
// mantissa halves are ~uniform -> ~25% of them have exp-field >= 0xC0.
__global__ __launch_bounds__(256) void detect_kernel(const u16* __restrict__ x,
                                                     int* __restrict__ flag){
  __shared__ int sh[256];
  int tid = threadIdx.x, cnt = 0;
  for (int i=tid; i<16384; i+=256){
    unsigned e = ((unsigned)x[i] >> 7) & 0xFFu;
    cnt += (e >= 0xC0u);
  }
  sh[tid] = cnt; __syncthreads();
  for (int s=128; s; s>>=1){ if (tid<s) sh[tid]+=sh[tid+s]; __syncthreads(); }
  if (tid==0) flag[0] = sh[0];
}

// ---------------- K0b: canonicalize weights/biases ----------------
__global__ __launch_bounds__(256) void convert_kernel(
    const void* __restrict__ w1, const void* __restrict__ w2,
    const void* __restrict__ b1, const void* __restrict__ b2,
    const int* __restrict__ flag,
    u16* __restrict__ w1b, u16* __restrict__ w2b,
    float* __restrict__ b1f, float* __restrict__ b2f){
  int isf = flag[0] > 64;
  int t = blockIdx.x*256 + threadIdx.x;       // 128 blocks -> 32768 threads
  size_t i8 = (size_t)t*8;                    // covers 262144 elements
  float f[8];
  load8(w1, i8, isf, f); store8b(w1b + i8, f);
  load8(w2, i8, isf, f); store8b(w2b + i8, f);
  if (t < 64){
    load8(b1, i8, isf, f);
#pragma unroll
    for (int j=0;j<8;j++) b1f[i8+j] = f[j];
    load8(b2, i8, isf, f);
#pragma unroll
    for (int j=0;j<8;j++) b2f[i8+j] = f[j];
  }
}

// ---------------- K1: per-sample sum / sumsq ----------------
__global__ __launch_bounds__(256) void stats_kernel(const void* __restrict__ x,
                                                    float* __restrict__ stats,
                                                    const int* __restrict__ flag){
  int isf = flag[0] > 64;
  int b   = blockIdx.y;
  int blk = blockIdx.x;                 // 16 blocks per sample
  size_t base = (size_t)b*NPER + (size_t)blk*32768;
  int tid = threadIdx.x;
  float s1 = 0.f, s2 = 0.f;
#pragma unroll
  for (int i=0;i<16;i++){
    float f[8];
    load8(x, base + i*2048 + tid*8, isf, f);
#pragma unroll
    for (int j=0;j<8;j++){ s1 += f[j]; s2 += f[j]*f[j]; }
  }
#pragma unroll
  for (int off=32; off; off>>=1){
    s1 += __shfl_down(s1, off);
    s2 += __shfl_down(s2, off);
  }
  __shared__ float r1[4], r2[4];
  int w = tid>>6, lane = tid&63;
  if (lane==0){ r1[w]=s1; r2[w]=s2; }
  __syncthreads();
  if (tid==0){
    atomicAdd(&stats[2*b],   r1[0]+r1[1]+r1[2]+r1[3]);
    atomicAdd(&stats[2*b+1], r2[0]+r2[1]+r2[2]+r2[3]);
  }
}

// ---------------- K2: LN + transpose to token-major xnT[s][c] (bf16) --------
__global__ __launch_bounds__(256) void lnT_kernel(const void* __restrict__ x,
                                                  const void* __restrict__ lw,
                                                  const void* __restrict__ lb,
                                                  const float* __restrict__ stats,
                                                  const int* __restrict__ flag,
                                                  int gb0,
                                                  u16* __restrict__ xnT){
  int isf = flag[0] > 64;
  int bl = blockIdx.z;                  // group-local sample
  int gb = gb0 + bl;                    // global sample
  int c0 = blockIdx.y*64;
  int s0 = blockIdx.x*64;
  const float invN = 1.f/(float)NPER;
  float mu  = stats[2*gb]*invN;
  float var = fmaxf(stats[2*gb+1]*invN - mu*mu, 0.f);
  float rs  = rsqrtf(var + 1e-5f);

  __shared__ float T[64][65];           // [c][s], pad -> conflict-free transpose
  int tid = threadIdx.x;
  int tr  = tid>>3;                     // 0..31
  int tcl = (tid&7)*8;                  // 0..56

#pragma unroll
  for (int p=0;p<2;p++){
    int c = c0 + p*32 + tr;
    size_t idx = (size_t)c*HWSZ + s0 + tcl;
    float xf[8], wf[8], bf_[8];
    load8(x,  (size_t)gb*NPER + idx, isf, xf);
    load8(lw, idx, isf, wf);
    load8(lb, idx, isf, bf_);
    float* dst = &T[p*32 + tr][tcl];
#pragma unroll
    for (int j=0;j<8;j++) dst[j] = (xf[j]-mu)*rs*wf[j] + bf_[j];
  }
  __syncthreads();
#pragma unroll
  for (int p=0;p<2;p++){
    int srow = p*32 + tr;
    float tmp[8];
#pragma unroll
    for (int j=0;j<8;j++) tmp[j] = T[tcl+j][srow];
    store8b(xnT + ((size_t)bl*HWSZ + s0 + srow)*CCH + c0 + tcl, tmp);
  }
}

// ---------------- K3/K4: NT GEMM, 128x128 tile, BK=64 ----------------
// C[m][n] = act( A[m][:] . B[n][:] + bias ), A,B row-major K-contiguous, K=512.
#define LDA 72
template<int RELU, int BIASM, int NT_LOG2, int NOUT, int DUALOUT>
__global__ __launch_bounds__(256) void gemm_kernel(
    const u16* __restrict__ A, long sA,
    const u16* __restrict__ B, long sB,
    const float* __restrict__ bias,
    u16* __restrict__ Co,
    const int* __restrict__ flag, int gb0)
{
  int b  = blockIdx.y;
  int tn = blockIdx.x & ((1<<NT_LOG2)-1);
  int tm = blockIdx.x >> NT_LOG2;
  const u16* Ab = A + (size_t)b*sA + (size_t)(tm*128)*512;
  const u16* Bb = B + (size_t)b*sB + (size_t)(tn*128)*512;

  __shared__ u16 As[128*LDA];
  __shared__ u16 Bs[128*LDA];

  int tid  = threadIdx.x;
  int lane = tid & 63;
  int w    = tid >> 6;
  int wm   = w >> 1, wn = w & 1;

  int rows[4], chs[4];
#pragma unroll
  for (int j=0;j<4;j++){
    int slot = j*256 + tid;             // 0..1023
    rows[j]  = slot >> 3;               // 0..127
    chs[j]   = (slot & 7)*8;            // element offset within k-tile
  }

  f32x4 acc[4][4];
#pragma unroll
  for (int i=0;i<4;i++)
#pragma unroll
    for (int j=0;j<4;j++) acc[i][j] = (f32x4){0.f,0.f,0.f,0.f};

  int l15 = lane & 15;
  int q   = lane >> 4;

  for (int kk=0; kk<512; kk+=64){
    uint4 av[4], bv[4];
#pragma unroll
    for (int j=0;j<4;j++) av[j] = *(const uint4*)(Ab + (size_t)rows[j]*512 + kk + chs[j]);
#pragma unroll
    for (int j=0;j<4;j++) bv[j] = *(const uint4*)(Bb + (size_t)rows[j]*512 + kk + chs[j]);
    __syncthreads();
#pragma unroll
    for (int j=0;j<4;j++) *(uint4*)(As + rows[j]*LDA + chs[j]) = av[j];
#pragma unroll
    for (int j=0;j<4;j++) *(uint4*)(Bs + rows[j]*LDA + chs[j]) = bv[j];
    __syncthreads();
#pragma unroll
    for (int ks=0; ks<2; ks++){
      bf16x8 fa[4], fb[4];
      int kco = (ks*4 + q)*8;
#pragma unroll
      for (int i=0;i<4;i++){
        int rowA = wm*64 + i*16 + l15;
        fa[i] = *(const bf16x8*)(As + rowA*LDA + kco);
        int rowB = wn*64 + i*16 + l15;
        fb[i] = *(const bf16x8*)(Bs + rowB*LDA + kco);
      }
#pragma unroll
      for (int i=0;i<4;i++)
#pragma unroll
        for (int jn=0;jn<4;jn++)
          acc[i][jn] = __builtin_amdgcn_mfma_f32_16x16x32_bf16(fa[i], fb[jn], acc[i][jn], 0,0,0);
    }
  }

  // epilogue: C/D layout col(n)=lane&15, row(m)=(lane>>4)*4+reg
  int isf = DUALOUT ? (flag[0] > 64) : 0;
  size_t sampOff = (size_t)(gb0 + b) * NPER;
  u16*   Cb = Co + sampOff;
  float* Cf = (float*)Co + sampOff;
  int col0 = tn*128 + wn*64;
  int row0 = tm*128 + wm*64;
#pragma unroll
  for (int i=0;i<4;i++){
#pragma unroll
    for (int jn=0;jn<4;jn++){
      int n = col0 + jn*16 + l15;
      float bn = BIASM ? 0.f : bias[n];
#pragma unroll
      for (int r=0;r<4;r++){
        int m = row0 + i*16 + q*4 + r;
        float v = acc[i][jn][r];
        v += BIASM ? bias[m] : bn;
        if (RELU) v = fmaxf(v, 0.f);
        if (DUALOUT && isf) Cf[(size_t)m*NOUT + n] = v;
        else                Cb[(size_t)m*NOUT + n] = f2b(v);
      }
    }
  }
}

extern "C" void kernel_launch(void* const* d_in, const int* in_sizes, int n_in,
                              void* d_out, int out_size, void* d_ws, size_t ws_size,
                              hipStream_t stream) {
  (void)in_sizes; (void)n_in; (void)out_size;
  const void* x  = d_in[0];
  const void* lw = d_in[1];
  const void* lb = d_in[2];
  const void* w1 = d_in[3];
  const void* b1 = d_in[4];
  const void* w2 = d_in[5];
  const void* b2 = d_in[6];

  char* ws = (char*)d_ws;
  float* stats = (float*)ws;                    // 256 floats
  int*   flag  = (int*)(ws + 1024);
  float* b1f   = (float*)(ws + 2048);
  float* b2f   = (float*)(ws + 4096);
  u16*   w1b   = (u16*)(ws + 8192);
  u16*   w2b   = (u16*)(ws + 8192 + 524288);
  u16*   xnT   = (u16*)(ws + (size_t)(2u<<20));

  // adaptive group size: per sample xnT (1 MiB) + hdnT (1 MiB)
  long gmax = ((long)ws_size - (2L<<20)) / (2L<<20);
  int G = (int)(gmax < 1 ? 1 : (gmax > 128 ? 128 : gmax));
  u16* hdnT = xnT + (size_t)G*NPER;

  hipMemsetAsync(d_ws, 0, 2048, stream);
  detect_kernel<<<1,256,0,stream>>>((const u16*)x, flag);
  convert_kernel<<<128,256,0,stream>>>(w1, w2, b1, b2, flag, w1b, w2b, b1f, b2f);
  stats_kernel<<<dim3(16,NSAMP),256,0,stream>>>(x, stats, flag);

  for (int b0=0; b0<NSAMP; b0+=G){
    int Gi = (NSAMP-b0 < G) ? (NSAMP-b0) : G;
    lnT_kernel<<<dim3(HWSZ/64, CCH/64, Gi),256,0,stream>>>(x, lw, lb, stats, flag, b0, xnT);
    // GEMM1: M=1024(s) N=512(d) -> hdnT[s][d], relu, bias on n, always bf16
    gemm_kernel<1,0,2,512,0><<<dim3(32,Gi),256,0,stream>>>(
        xnT, (long)NPER, w1b, 0L, b1f, hdnT, flag, 0);
    // GEMM2: M=512(e) N=1024(s) -> out[e][s], bias on m, dtype per flag
    gemm_kernel<0,1,3,1024,1><<<dim3(32,Gi),256,0,stream>>>(
        w2b, 0L, hdnT, (long)NPER, b2f, (u16*)d_out, flag, b0);
  }
}